// Round 3
// baseline (558.789 us; speedup 1.0000x reference)
//
#include <hip/hip_runtime.h>
#include <stdint.h>

// ---------------------------------------------------------------------------
// aggregated_embedding: heap binary-tree aggregation, 11 levels.
// out = root + (elu(elu(x@WinT+b_in)@W1T+b1)@W2T+b2), x=[root,left,right]
// bf16 MFMA 16x16x32, fp32 accumulate. Round 3:
//  - vmcnt-order fix: gathers issued AFTER all B-loads of a pass (kstep 6)
//  - launch_bounds(256,3): real prefetch registers (unified VGPR+AGPR ~170)
//  - coalesced bf16 stores via LDS staging (kill 2B-scatter RMW writes)
//  - tail fusion: levels 32..1 in ONE kernel (1 block/batch, LDS-resident)
// ws layout:
//   [0)            Ebf   32064*256 bf16
//   [16,416,768)   Winbf 256*768  bf16   (row-major [n][k] = MFMA B-frag order)
//   [16,809,984)   W1bf  256*256  bf16
//   [16,941,056)   W2bf  256*256  bf16
//   [17,072,128)   curA  64*1024*256 bf16
//   [50,626,560)   curB  64*512*256 bf16
// ---------------------------------------------------------------------------

typedef __attribute__((ext_vector_type(8))) short short8;   // 8 x bf16 frag
typedef __attribute__((ext_vector_type(4))) float f32x4;    // MFMA C/D

#define XS_STRIDE 264   // 256+8 pad: 528B row stride, b128-aligned, 2-way alias only
#define TOK_N 4095

__device__ __forceinline__ unsigned short f32_to_bf16(float f) {
    union { float f; unsigned u; } v; v.f = f;
    return (unsigned short)((v.u + 0x7fffu + ((v.u >> 16) & 1u)) >> 16);  // RNE
}
__device__ __forceinline__ float bf16_to_f32(unsigned short u) {
    union { unsigned u; float f; } v; v.u = ((unsigned)u) << 16; return v.f;
}

__global__ void convert_f32_bf16(const float* __restrict__ E,
                                 const float* __restrict__ Win,
                                 const float* __restrict__ W1,
                                 const float* __restrict__ W2,
                                 unsigned short* __restrict__ Ebf,
                                 unsigned short* __restrict__ Winbf,
                                 unsigned short* __restrict__ W1bf,
                                 unsigned short* __restrict__ W2bf) {
    const int nE = 32064 * 256, nWin = 256 * 768, nW = 256 * 256;
    const int total4 = (nE + nWin + 2 * nW) >> 2;
    for (int i = blockIdx.x * blockDim.x + threadIdx.x; i < total4;
         i += gridDim.x * blockDim.x) {
        int idx = i << 2;
        const float* src; unsigned short* dst; int off;
        if (idx < nE)                  { src = E;   dst = Ebf;   off = idx; }
        else if (idx < nE + nWin)      { src = Win; dst = Winbf; off = idx - nE; }
        else if (idx < nE + nWin + nW) { src = W1;  dst = W1bf;  off = idx - nE - nWin; }
        else                           { src = W2;  dst = W2bf;  off = idx - nE - nWin - nW; }
        float4 f = *(const float4*)(src + off);
        ushort4 o;
        o.x = f32_to_bf16(f.x); o.y = f32_to_bf16(f.y);
        o.z = f32_to_bf16(f.z); o.w = f32_to_bf16(f.w);
        *(ushort4*)(dst + off) = o;
    }
}

// ---------------------------------------------------------------------------
// One K=256 MFMA pass: A-frags from LDS, B-frags rolling-preloaded from L2.
// late() is called at kstep 6 — AFTER the last B-load of this pass has been
// issued, so gather latency never blocks a B-frag vmcnt wait (in-order cnt).
// ---------------------------------------------------------------------------
template<int MT, int DEPTH, int WROW, typename F>
__device__ __forceinline__ void run_pass(const unsigned short* __restrict__ Xs,
                                         const unsigned short* __restrict__ wlane,
                                         int kbase, f32x4 (&acc)[MT][4],
                                         int l15, int q, F&& late)
{
    short8 bb[DEPTH][4];
#pragma unroll
    for (int d = 0; d < DEPTH; ++d)
#pragma unroll
        for (int nt = 0; nt < 4; ++nt)
            bb[d][nt] = *(const short8*)(wlane + (size_t)(nt * 16) * WROW + kbase + d * 32);
#pragma unroll
    for (int k = 0; k < 8; ++k) {
        if (k == 6) { __builtin_amdgcn_sched_barrier(0); late(); }
        short8 a[MT];
#pragma unroll
        for (int mt = 0; mt < MT; ++mt)
            a[mt] = *(const short8*)(&Xs[(mt * 16 + l15) * XS_STRIDE + k * 32 + q * 8]);
#pragma unroll
        for (int mt = 0; mt < MT; ++mt)
#pragma unroll
            for (int nt = 0; nt < 4; ++nt)
                acc[mt][nt] = __builtin_amdgcn_mfma_f32_16x16x32_bf16(
                    a[mt], bb[k % DEPTH][nt], acc[mt][nt], 0, 0, 0);
        if (k + DEPTH < 8) {
#pragma unroll
            for (int nt = 0; nt < 4; ++nt)
                bb[k % DEPTH][nt] = *(const short8*)(wlane + (size_t)(nt * 16) * WROW + kbase + (k + DEPTH) * 32);
        }
    }
}

// ---------------------------------------------------------------------------
// tree_level<MT>: block = 256 thr (4 waves), R = MT*16 rows x 256 cols.
// Handles levels 1024..64 (never the last level).
// ---------------------------------------------------------------------------
template<int MT>
__global__ __launch_bounds__(256, 3)
void tree_level(const int* __restrict__ tokens,
                const unsigned short* __restrict__ Ebf,
                const unsigned short* __restrict__ Win,
                const unsigned short* __restrict__ W1,
                const unsigned short* __restrict__ W2,
                const float* __restrict__ b_in,
                const float* __restrict__ b1,
                const float* __restrict__ b2,
                const unsigned short* __restrict__ cur_in,
                unsigned short* __restrict__ cur_out,
                int L, int logL, int first)
{
    constexpr int R = MT * 16;
    constexpr int GITER = R / 8;
    constexpr int DEPTH = (MT >= 4) ? 2 : 4;
    __shared__ unsigned short Xs[R * XS_STRIDE];

    const int tid  = threadIdx.x;
    const int lane = tid & 63;
    const int wid  = tid >> 6;
    const int l15  = lane & 15;
    const int q    = lane >> 4;
    const int n0   = wid * 64;
    const int blk  = blockIdx.x;
    const int c    = tid & 31;
    const int sub  = tid >> 5;

    auto gsrc = [&](int p, int r) -> const unsigned short* {
        int g = blk * R + r;
        int b = g >> logL;
        int i = g - (b << logL);
        if (p == 0) {
            int tok = tokens[b * TOK_N + (L - 1) + i];
            return Ebf + (size_t)tok * 256;
        } else if (first) {
            int tok = tokens[b * TOK_N + 2047 + 2 * i + (p - 1)];
            return Ebf + (size_t)tok * 256;
        } else {
            return cur_in + ((size_t)b * (2 * L) + 2 * i + (p - 1)) * 256;
        }
    };

    short8 g[GITER];

    // phase-0 gather (root) — written immediately, so it never poisons vmcnt
#pragma unroll
    for (int it = 0; it < GITER; ++it)
        g[it] = *(const short8*)(gsrc(0, it * 8 + sub) + c * 8);
#pragma unroll
    for (int it = 0; it < GITER; ++it)
        *(short8*)(&Xs[(it * 8 + sub) * XS_STRIDE + c * 8]) = g[it];
    __syncthreads();

    f32x4 acc[MT][4];
    float bv[4];
#pragma unroll
    for (int nt = 0; nt < 4; ++nt) bv[nt] = b_in[n0 + nt * 16 + l15];
#pragma unroll
    for (int mt = 0; mt < MT; ++mt)
#pragma unroll
        for (int nt = 0; nt < 4; ++nt)
            acc[mt][nt] = (f32x4){bv[nt], bv[nt], bv[nt], bv[nt]};

    // GEMM1: 3 phases of K=256 vs Win; next-phase gather issued at kstep 6
    const unsigned short* winlane = Win + q * 8 + (size_t)(n0 + l15) * 768;
    for (int p = 0; p < 3; ++p) {
        run_pass<MT, DEPTH, 768>(Xs, winlane, p * 256, acc, l15, q, [&]() {
            if (p < 2) {
#pragma unroll
                for (int it = 0; it < GITER; ++it)
                    g[it] = *(const short8*)(gsrc(p + 1, it * 8 + sub) + c * 8);
            }
        });
        __syncthreads();
        if (p < 2) {
#pragma unroll
            for (int it = 0; it < GITER; ++it)
                *(short8*)(&Xs[(it * 8 + sub) * XS_STRIDE + c * 8]) = g[it];
            __syncthreads();
        }
    }

    // epilogue 1: Xs = bf16(elu(H1)) in place
#pragma unroll
    for (int mt = 0; mt < MT; ++mt)
#pragma unroll
        for (int nt = 0; nt < 4; ++nt)
#pragma unroll
            for (int r = 0; r < 4; ++r) {
                float h = acc[mt][nt][r];
                h = h > 0.f ? h : (__expf(h) - 1.f);
                Xs[(mt * 16 + q * 4 + r) * XS_STRIDE + n0 + nt * 16 + l15] = f32_to_bf16(h);
            }
    __syncthreads();

    // GEMM2
#pragma unroll
    for (int nt = 0; nt < 4; ++nt) bv[nt] = b1[n0 + nt * 16 + l15];
#pragma unroll
    for (int mt = 0; mt < MT; ++mt)
#pragma unroll
        for (int nt = 0; nt < 4; ++nt)
            acc[mt][nt] = (f32x4){bv[nt], bv[nt], bv[nt], bv[nt]};
    run_pass<MT, DEPTH, 256>(Xs, W1 + q * 8 + (size_t)(n0 + l15) * 256, 0,
                             acc, l15, q, []() {});
    __syncthreads();

    // epilogue 2: Xs = bf16(elu(H2)) in place
#pragma unroll
    for (int mt = 0; mt < MT; ++mt)
#pragma unroll
        for (int nt = 0; nt < 4; ++nt)
#pragma unroll
            for (int r = 0; r < 4; ++r) {
                float h = acc[mt][nt][r];
                h = h > 0.f ? h : (__expf(h) - 1.f);
                Xs[(mt * 16 + q * 4 + r) * XS_STRIDE + n0 + nt * 16 + l15] = f32_to_bf16(h);
            }
    __syncthreads();

    // GEMM3; root residual re-gather issued at kstep 6 (after all B-loads)
#pragma unroll
    for (int nt = 0; nt < 4; ++nt) bv[nt] = b2[n0 + nt * 16 + l15];
#pragma unroll
    for (int mt = 0; mt < MT; ++mt)
#pragma unroll
        for (int nt = 0; nt < 4; ++nt)
            acc[mt][nt] = (f32x4){bv[nt], bv[nt], bv[nt], bv[nt]};
    run_pass<MT, DEPTH, 256>(Xs, W2 + q * 8 + (size_t)(n0 + l15) * 256, 0,
                             acc, l15, q, [&]() {
#pragma unroll
        for (int it = 0; it < GITER; ++it)
            g[it] = *(const short8*)(gsrc(0, it * 8 + sub) + c * 8);
    });
    __syncthreads();

    // park root in Xs (transpose to [row][col] access)
#pragma unroll
    for (int it = 0; it < GITER; ++it)
        *(short8*)(&Xs[(it * 8 + sub) * XS_STRIDE + c * 8]) = g[it];
    __syncthreads();

    // epilogue 3: o = root + H3 (+b2 in acc); rewrite Xs in place (lane-private)
#pragma unroll
    for (int mt = 0; mt < MT; ++mt)
#pragma unroll
        for (int nt = 0; nt < 4; ++nt)
#pragma unroll
            for (int r = 0; r < 4; ++r) {
                int row = mt * 16 + q * 4 + r;
                int col = n0 + nt * 16 + l15;
                float o = acc[mt][nt][r] + bf16_to_f32(Xs[row * XS_STRIDE + col]);
                Xs[row * XS_STRIDE + col] = f32_to_bf16(o);
            }
    __syncthreads();

    // coalesced bf16 store
#pragma unroll
    for (int it = 0; it < GITER; ++it)
        *(short8*)(cur_out + ((size_t)(blk * R + it * 8 + sub)) * 256 + c * 8) =
            *(const short8*)(&Xs[(it * 8 + sub) * XS_STRIDE + c * 8]);
}

// ---------------------------------------------------------------------------
// tree_tail: levels 32..1 fused. One block per batch (64 blocks); children
// kept in LDS across levels; final level writes fp32 output.
// ---------------------------------------------------------------------------
__global__ __launch_bounds__(256, 2)
void tree_tail(const int* __restrict__ tokens,
               const unsigned short* __restrict__ Ebf,
               const unsigned short* __restrict__ Win,
               const unsigned short* __restrict__ W1,
               const unsigned short* __restrict__ W2,
               const float* __restrict__ b_in,
               const float* __restrict__ b1,
               const float* __restrict__ b2,
               const unsigned short* __restrict__ cur_in,  // level-64 out, 64 rows/batch
               float* __restrict__ out)
{
    __shared__ unsigned short prev[64 * 256];
    __shared__ unsigned short Xs[32 * XS_STRIDE];
    constexpr int MT = 2, GITER = 4, DEPTH = 4;

    const int b    = blockIdx.x;
    const int tid  = threadIdx.x;
    const int lane = tid & 63;
    const int wid  = tid >> 6;
    const int l15  = lane & 15;
    const int q    = lane >> 4;
    const int n0   = wid * 64;
    const int c    = tid & 31;
    const int sub  = tid >> 5;

    // preload children of level 32 (= level-64 outputs), coalesced
#pragma unroll
    for (int it = 0; it < 8; ++it) {
        int idx = it * 256 + tid;
        *(short8*)(&prev[idx * 8]) = *(const short8*)(cur_in + (size_t)b * 64 * 256 + idx * 8);
    }
    __syncthreads();

    const unsigned short* winlane = Win + q * 8 + (size_t)(n0 + l15) * 768;
    const unsigned short* w1lane  = W1  + q * 8 + (size_t)(n0 + l15) * 256;
    const unsigned short* w2lane  = W2  + q * 8 + (size_t)(n0 + l15) * 256;

    f32x4 acc[MT][4];
    float bv[4];
    short8 g[GITER];

    for (int L = 32; L >= 1; L >>= 1) {
        // root gather (held in g for the residual)
#pragma unroll
        for (int it = 0; it < GITER; ++it) {
            int r = it * 8 + sub;
            int i = (r < L) ? r : 0;
            int tok = tokens[b * TOK_N + (L - 1) + i];
            g[it] = *(const short8*)(Ebf + (size_t)tok * 256 + c * 8);
        }
#pragma unroll
        for (int it = 0; it < GITER; ++it)
            *(short8*)(&Xs[(it * 8 + sub) * XS_STRIDE + c * 8]) = g[it];
        __syncthreads();

#pragma unroll
        for (int nt = 0; nt < 4; ++nt) bv[nt] = b_in[n0 + nt * 16 + l15];
#pragma unroll
        for (int mt = 0; mt < MT; ++mt)
#pragma unroll
            for (int nt = 0; nt < 4; ++nt)
                acc[mt][nt] = (f32x4){bv[nt], bv[nt], bv[nt], bv[nt]};

        run_pass<MT, DEPTH, 768>(Xs, winlane, 0, acc, l15, q, []() {});
        __syncthreads();
        // children phases from LDS prev
        for (int p = 1; p <= 2; ++p) {
#pragma unroll
            for (int it = 0; it < GITER; ++it) {
                int r = it * 8 + sub;
                int i = (r < L) ? r : 0;
                *(short8*)(&Xs[r * XS_STRIDE + c * 8]) =
                    *(const short8*)(&prev[(2 * i + (p - 1)) * 256 + c * 8]);
            }
            __syncthreads();
            run_pass<MT, DEPTH, 768>(Xs, winlane, p * 256, acc, l15, q, []() {});
            __syncthreads();
        }

        // ep1
#pragma unroll
        for (int mt = 0; mt < MT; ++mt)
#pragma unroll
            for (int nt = 0; nt < 4; ++nt)
#pragma unroll
                for (int r = 0; r < 4; ++r) {
                    float h = acc[mt][nt][r];
                    h = h > 0.f ? h : (__expf(h) - 1.f);
                    Xs[(mt * 16 + q * 4 + r) * XS_STRIDE + n0 + nt * 16 + l15] = f32_to_bf16(h);
                }
        __syncthreads();

#pragma unroll
        for (int nt = 0; nt < 4; ++nt) bv[nt] = b1[n0 + nt * 16 + l15];
#pragma unroll
        for (int mt = 0; mt < MT; ++mt)
#pragma unroll
            for (int nt = 0; nt < 4; ++nt)
                acc[mt][nt] = (f32x4){bv[nt], bv[nt], bv[nt], bv[nt]};
        run_pass<MT, DEPTH, 256>(Xs, w1lane, 0, acc, l15, q, []() {});
        __syncthreads();

        // ep2
#pragma unroll
        for (int mt = 0; mt < MT; ++mt)
#pragma unroll
            for (int nt = 0; nt < 4; ++nt)
#pragma unroll
                for (int r = 0; r < 4; ++r) {
                    float h = acc[mt][nt][r];
                    h = h > 0.f ? h : (__expf(h) - 1.f);
                    Xs[(mt * 16 + q * 4 + r) * XS_STRIDE + n0 + nt * 16 + l15] = f32_to_bf16(h);
                }
        __syncthreads();

#pragma unroll
        for (int nt = 0; nt < 4; ++nt) bv[nt] = b2[n0 + nt * 16 + l15];
#pragma unroll
        for (int mt = 0; mt < MT; ++mt)
#pragma unroll
            for (int nt = 0; nt < 4; ++nt)
                acc[mt][nt] = (f32x4){bv[nt], bv[nt], bv[nt], bv[nt]};
        run_pass<MT, DEPTH, 256>(Xs, w2lane, 0, acc, l15, q, []() {});
        __syncthreads();

        // park root (from g, still live) for transposed access
#pragma unroll
        for (int it = 0; it < GITER; ++it)
            *(short8*)(&Xs[(it * 8 + sub) * XS_STRIDE + c * 8]) = g[it];
        __syncthreads();

        // ep3: o = root + H3; write next-level children / final output
#pragma unroll
        for (int mt = 0; mt < MT; ++mt)
#pragma unroll
            for (int nt = 0; nt < 4; ++nt)
#pragma unroll
                for (int r = 0; r < 4; ++r) {
                    int row = mt * 16 + q * 4 + r;
                    int col = n0 + nt * 16 + l15;
                    float o = acc[mt][nt][r] + bf16_to_f32(Xs[row * XS_STRIDE + col]);
                    if (row < L) {
                        if (L == 1) out[(size_t)b * 256 + col] = o;
                        else        prev[row * 256 + col] = f32_to_bf16(o);
                    }
                }
        __syncthreads();
    }
}

extern "C" void kernel_launch(void* const* d_in, const int* in_sizes, int n_in,
                              void* d_out, int out_size, void* d_ws, size_t ws_size,
                              hipStream_t stream) {
    const int*   tokens = (const int*)  d_in[0];
    const float* E      = (const float*)d_in[1];
    const float* W_in   = (const float*)d_in[2];
    const float* b_in   = (const float*)d_in[3];
    const float* W1     = (const float*)d_in[4];
    const float* b1     = (const float*)d_in[5];
    const float* W2     = (const float*)d_in[6];
    const float* b2     = (const float*)d_in[7];
    float* out = (float*)d_out;
    char* ws = (char*)d_ws;

    unsigned short* Ebf   = (unsigned short*)(ws);
    unsigned short* Winbf = (unsigned short*)(ws + 16416768);
    unsigned short* W1bf  = (unsigned short*)(ws + 16809984);
    unsigned short* W2bf  = (unsigned short*)(ws + 16941056);
    unsigned short* curA  = (unsigned short*)(ws + 17072128);
    unsigned short* curB  = (unsigned short*)(ws + 50626560);

    convert_f32_bf16<<<1024, 256, 0, stream>>>(E, W_in, W1, W2,
                                               Ebf, Winbf, W1bf, W2bf);

    const unsigned short* cin = curB;   // unused at first level
    unsigned short* cout = curA;
    int first = 1;
    for (int L = 1024; L >= 64; L >>= 1) {
        int logL = 31 - __builtin_clz((unsigned)L);
        int MTs = (L >= 512) ? 4 : (L == 256 ? 2 : 1);
        int blocks = (64 * L) / (16 * MTs);
        if (MTs == 4)
            tree_level<4><<<dim3(blocks), dim3(256), 0, stream>>>(
                tokens, Ebf, Winbf, W1bf, W2bf, b_in, b1, b2, cin, cout, L, logL, first);
        else if (MTs == 2)
            tree_level<2><<<dim3(blocks), dim3(256), 0, stream>>>(
                tokens, Ebf, Winbf, W1bf, W2bf, b_in, b1, b2, cin, cout, L, logL, first);
        else
            tree_level<1><<<dim3(blocks), dim3(256), 0, stream>>>(
                tokens, Ebf, Winbf, W1bf, W2bf, b_in, b1, b2, cin, cout, L, logL, first);
        cin = cout;
        cout = (cout == curA) ? curB : curA;
        first = 0;
    }
    // cin now points at the level-64 output (curA)
    tree_tail<<<dim3(64), dim3(256), 0, stream>>>(
        tokens, Ebf, Winbf, W1bf, W2bf, b_in, b1, b2, cin, out);
}

// Round 4
// 542.112 us; speedup vs baseline: 1.0308x; 1.0308x over previous
//
#include <hip/hip_runtime.h>
#include <stdint.h>

// ---------------------------------------------------------------------------
// aggregated_embedding: heap binary-tree aggregation, 11 levels.
// out = root + (elu(elu(x@WinT+b_in)@W1T+b1)@W2T+b2), x=[root,left,right]
// bf16 MFMA 16x16x32, fp32 accumulate. Round 4:
//  - gathers via __builtin_amdgcn_global_load_lds (0 VGPRs, async DMA)
//  - XOR-swizzled LDS (slot = chunk ^ (row&7)): unpadded 512B rows, since
//    global_load_lds forces lane*16 LDS layout; swizzle keeps ds_read_b128
//    conflict-optimal. All LDS accessors use the same swizzle.
//  - registers freed -> DEPTH-2/4 rolling B preload is real (LB(256,3))
//  - tail fusion REVERTED (R3 post-mortem: 183us at 2.8% occupancy);
//    per-level launches down to L=1, MT=4/2/1; last level writes fp32 direct.
// ws layout:
//   [0)            Ebf   32064*256 bf16
//   [16,416,768)   Winbf 256*768  bf16   (row-major [n][k] = MFMA B-frag order)
//   [16,809,984)   W1bf  256*256  bf16
//   [16,941,056)   W2bf  256*256  bf16
//   [17,072,128)   curA  64*1024*256 bf16
//   [50,626,560)   curB  64*512*256 bf16
// ---------------------------------------------------------------------------

typedef __attribute__((ext_vector_type(8))) short short8;   // 8 x bf16 frag
typedef __attribute__((ext_vector_type(4))) float f32x4;    // MFMA C/D

typedef const __attribute__((address_space(1))) unsigned int* gas_ptr;
typedef __attribute__((address_space(3))) unsigned int* las_ptr;

#define TOK_N 4095

__device__ __forceinline__ unsigned short f32_to_bf16(float f) {
    union { float f; unsigned u; } v; v.f = f;
    return (unsigned short)((v.u + 0x7fffu + ((v.u >> 16) & 1u)) >> 16);  // RNE
}
__device__ __forceinline__ float bf16_to_f32(unsigned short u) {
    union { unsigned u; float f; } v; v.u = ((unsigned)u) << 16; return v.f;
}

__global__ void convert_f32_bf16(const float* __restrict__ E,
                                 const float* __restrict__ Win,
                                 const float* __restrict__ W1,
                                 const float* __restrict__ W2,
                                 unsigned short* __restrict__ Ebf,
                                 unsigned short* __restrict__ Winbf,
                                 unsigned short* __restrict__ W1bf,
                                 unsigned short* __restrict__ W2bf) {
    const int nE = 32064 * 256, nWin = 256 * 768, nW = 256 * 256;
    const int total4 = (nE + nWin + 2 * nW) >> 2;
    for (int i = blockIdx.x * blockDim.x + threadIdx.x; i < total4;
         i += gridDim.x * blockDim.x) {
        int idx = i << 2;
        const float* src; unsigned short* dst; int off;
        if (idx < nE)                  { src = E;   dst = Ebf;   off = idx; }
        else if (idx < nE + nWin)      { src = Win; dst = Winbf; off = idx - nE; }
        else if (idx < nE + nWin + nW) { src = W1;  dst = W1bf;  off = idx - nE - nWin; }
        else                           { src = W2;  dst = W2bf;  off = idx - nE - nWin - nW; }
        float4 f = *(const float4*)(src + off);
        ushort4 o;
        o.x = f32_to_bf16(f.x); o.y = f32_to_bf16(f.y);
        o.z = f32_to_bf16(f.z); o.w = f32_to_bf16(f.w);
        *(ushort4*)(dst + off) = o;
    }
}

// ---------------------------------------------------------------------------
// One K=256 MFMA pass. A-frags from swizzled LDS (ds_read_b128), B-frags
// rolling-preloaded from L2 (DEPTH deep). Swizzle: chunk (4k+q) of row r
// lives at slot (4k+q)^(r&7); for a-frags r = mt*16+l15 so r&7 == l15&7.
// ---------------------------------------------------------------------------
template<int MT, int DEPTH, int WROW>
__device__ __forceinline__ void run_pass(const unsigned short* __restrict__ Xs,
                                         const unsigned short* __restrict__ wlane,
                                         int kbase, f32x4 (&acc)[MT][4],
                                         int l15, int q)
{
    const int xm = l15 & 7;
    short8 bb[DEPTH][4];
#pragma unroll
    for (int d = 0; d < DEPTH; ++d)
#pragma unroll
        for (int nt = 0; nt < 4; ++nt)
            bb[d][nt] = *(const short8*)(wlane + (size_t)(nt * 16) * WROW + kbase + d * 32);
#pragma unroll
    for (int k = 0; k < 8; ++k) {
        short8 a[MT];
        const int sl = (((4 * k + q) ^ xm) << 3);       // swizzled chunk * 8
#pragma unroll
        for (int mt = 0; mt < MT; ++mt)
            a[mt] = *(const short8*)(Xs + (mt * 16 + l15) * 256 + sl);
#pragma unroll
        for (int mt = 0; mt < MT; ++mt)
#pragma unroll
            for (int nt = 0; nt < 4; ++nt)
                acc[mt][nt] = __builtin_amdgcn_mfma_f32_16x16x32_bf16(
                    a[mt], bb[k % DEPTH][nt], acc[mt][nt], 0, 0, 0);
        if (k + DEPTH < 8) {
#pragma unroll
            for (int nt = 0; nt < 4; ++nt)
                bb[k % DEPTH][nt] = *(const short8*)(wlane + (size_t)(nt * 16) * WROW + kbase + (k + DEPTH) * 32);
        }
    }
}

// ---------------------------------------------------------------------------
// tree_level<MT,LAST>: block = 256 thr (4 waves), R = MT*16 rows x 256 cols.
// ---------------------------------------------------------------------------
template<int MT, int LAST>
__global__ __launch_bounds__(256, 3)
void tree_level(const int* __restrict__ tokens,
                const unsigned short* __restrict__ Ebf,
                const unsigned short* __restrict__ Win,
                const unsigned short* __restrict__ W1,
                const unsigned short* __restrict__ W2,
                const float* __restrict__ b_in,
                const float* __restrict__ b1,
                const float* __restrict__ b2,
                const unsigned short* __restrict__ cur_in,
                unsigned short* __restrict__ cur_out,
                float* __restrict__ final_out,
                int L, int logL, int first)
{
    constexpr int R = MT * 16;
    constexpr int DEPTH = (MT >= 4) ? 2 : 4;
    __shared__ unsigned short Xs[R * 256];   // unpadded, XOR-swizzled

    const int tid  = threadIdx.x;
    const int lane = tid & 63;
    const int wid  = tid >> 6;
    const int l15  = lane & 15;
    const int q    = lane >> 4;
    const int n0   = wid * 64;
    const int blk  = blockIdx.x;

    // async gather of one 256-elem phase into Xs (swizzled). One instr moves
    // 2 rows (64 lanes x 16B); wave w covers rows [w*R/4, (w+1)*R/4).
    auto gather = [&](int p) {
#pragma unroll
        for (int t = 0; t < R / 8; ++t) {
            const int base_r = wid * (R / 4) + t * 2;
            const int r = base_r + (lane >> 5);
            const unsigned short* src;
            {
                int g = blk * R + r;
                int b = g >> logL;
                int i = g - (b << logL);
                if (p == 0) {
                    int tok = tokens[b * TOK_N + (L - 1) + i];
                    src = Ebf + (size_t)tok * 256;
                } else if (first) {
                    int tok = tokens[b * TOK_N + 2047 + 2 * i + (p - 1)];
                    src = Ebf + (size_t)tok * 256;
                } else {
                    src = cur_in + ((size_t)b * (2 * L) + 2 * i + (p - 1)) * 256;
                }
            }
            const int c = (lane & 31) ^ (r & 7);         // chunk for my slot
            __builtin_amdgcn_global_load_lds(
                (gas_ptr)(const void*)(src + c * 8),
                (las_ptr)(void*)(Xs + base_r * 256), 16, 0, 0);
        }
    };

    f32x4 acc[MT][4];
    float bv[4];
    auto init_acc = [&](const float* __restrict__ bias) {
#pragma unroll
        for (int nt = 0; nt < 4; ++nt) bv[nt] = bias[n0 + nt * 16 + l15];
#pragma unroll
        for (int mt = 0; mt < MT; ++mt)
#pragma unroll
            for (int nt = 0; nt < 4; ++nt)
                acc[mt][nt] = (f32x4){bv[nt], bv[nt], bv[nt], bv[nt]};
    };
    // C-layout epilogue -> swizzled Xs (elu + bf16)
    auto store_elu = [&]() {
#pragma unroll
        for (int mt = 0; mt < MT; ++mt)
#pragma unroll
            for (int nt = 0; nt < 4; ++nt)
#pragma unroll
                for (int rr = 0; rr < 4; ++rr) {
                    int row = mt * 16 + q * 4 + rr;
                    int col = n0 + nt * 16 + l15;
                    float h = acc[mt][nt][rr];
                    h = h > 0.f ? h : (__expf(h) - 1.f);
                    int slot = (col >> 3) ^ (row & 7);
                    Xs[row * 256 + slot * 8 + (col & 7)] = f32_to_bf16(h);
                }
    };

    // ---- GEMM1: 3 phases of K=256 vs Win --------------------------------
    gather(0);
    __syncthreads();                      // drains vmcnt (global_load_lds)
    init_acc(b_in);
    const unsigned short* winlane = Win + q * 8 + (size_t)(n0 + l15) * 768;
    for (int p = 0; p < 3; ++p) {
        run_pass<MT, DEPTH, 768>(Xs, winlane, p * 256, acc, l15, q);
        __syncthreads();                  // all waves done reading Xs
        if (p < 2) {
            gather(p + 1);
            __syncthreads();
        }
    }
    store_elu();
    __syncthreads();

    // ---- GEMM2 ----------------------------------------------------------
    init_acc(b1);
    run_pass<MT, DEPTH, 256>(Xs, W1 + q * 8 + (size_t)(n0 + l15) * 256, 0, acc, l15, q);
    __syncthreads();
    store_elu();
    __syncthreads();

    // ---- GEMM3 ----------------------------------------------------------
    init_acc(b2);
    run_pass<MT, DEPTH, 256>(Xs, W2 + q * 8 + (size_t)(n0 + l15) * 256, 0, acc, l15, q);
    __syncthreads();

    // ---- root residual re-gather (bf16) into Xs -------------------------
    gather(0);
    __syncthreads();

    // ---- epilogue 3: o = root + H3 (+b2 in acc), no elu -----------------
    if (LAST) {
        // write fp32 directly (tiny level; precision: no extra bf16 round)
#pragma unroll
        for (int mt = 0; mt < MT; ++mt)
#pragma unroll
            for (int nt = 0; nt < 4; ++nt)
#pragma unroll
                for (int rr = 0; rr < 4; ++rr) {
                    int row = mt * 16 + q * 4 + rr;
                    int col = n0 + nt * 16 + l15;
                    int slot = (col >> 3) ^ (row & 7);
                    float o = acc[mt][nt][rr] +
                              bf16_to_f32(Xs[row * 256 + slot * 8 + (col & 7)]);
                    final_out[(size_t)(blk * R + row) * 256 + col] = o;
                }
    } else {
#pragma unroll
        for (int mt = 0; mt < MT; ++mt)
#pragma unroll
            for (int nt = 0; nt < 4; ++nt)
#pragma unroll
                for (int rr = 0; rr < 4; ++rr) {
                    int row = mt * 16 + q * 4 + rr;
                    int col = n0 + nt * 16 + l15;
                    int slot = (col >> 3) ^ (row & 7);
                    int a = row * 256 + slot * 8 + (col & 7);
                    float o = acc[mt][nt][rr] + bf16_to_f32(Xs[a]);
                    Xs[a] = f32_to_bf16(o);     // same addr: lane-private
                }
        __syncthreads();
        // coalesced bf16 store (16B chunks, de-swizzled address)
        const int s  = tid & 31;
        const int sub = tid >> 5;
#pragma unroll
        for (int it = 0; it < R / 8; ++it) {
            int r = it * 8 + sub;
            int c = s ^ (r & 7);
            *(short8*)(cur_out + (size_t)(blk * R + r) * 256 + c * 8) =
                *(const short8*)(Xs + r * 256 + s * 8);
        }
    }
}

template<int MT, int LAST>
static void launch_level(const int* tokens, const unsigned short* Ebf,
                         const unsigned short* Win, const unsigned short* W1,
                         const unsigned short* W2, const float* b_in,
                         const float* b1, const float* b2,
                         const unsigned short* cin, unsigned short* cout,
                         float* out, int L, int first, hipStream_t stream) {
    int logL = 31 - __builtin_clz((unsigned)L);
    int blocks = (64 * L) / (16 * MT);
    tree_level<MT, LAST><<<dim3(blocks), dim3(256), 0, stream>>>(
        tokens, Ebf, Win, W1, W2, b_in, b1, b2, cin, cout, out, L, logL, first);
}

extern "C" void kernel_launch(void* const* d_in, const int* in_sizes, int n_in,
                              void* d_out, int out_size, void* d_ws, size_t ws_size,
                              hipStream_t stream) {
    const int*   tokens = (const int*)  d_in[0];
    const float* E      = (const float*)d_in[1];
    const float* W_in   = (const float*)d_in[2];
    const float* b_in   = (const float*)d_in[3];
    const float* W1     = (const float*)d_in[4];
    const float* b1     = (const float*)d_in[5];
    const float* W2     = (const float*)d_in[6];
    const float* b2     = (const float*)d_in[7];
    float* out = (float*)d_out;
    char* ws = (char*)d_ws;

    unsigned short* Ebf   = (unsigned short*)(ws);
    unsigned short* Winbf = (unsigned short*)(ws + 16416768);
    unsigned short* W1bf  = (unsigned short*)(ws + 16809984);
    unsigned short* W2bf  = (unsigned short*)(ws + 16941056);
    unsigned short* curA  = (unsigned short*)(ws + 17072128);
    unsigned short* curB  = (unsigned short*)(ws + 50626560);

    convert_f32_bf16<<<1024, 256, 0, stream>>>(E, W_in, W1, W2,
                                               Ebf, Winbf, W1bf, W2bf);

    const unsigned short* cin = curB;   // unused at first level
    unsigned short* cout = curA;
    int first = 1;
    for (int L = 1024; L >= 1; L >>= 1) {
        int last = (L == 1);
        if (L >= 512)
            launch_level<4, 0>(tokens, Ebf, Winbf, W1bf, W2bf, b_in, b1, b2,
                               cin, cout, nullptr, L, first, stream);
        else if (L >= 128)
            launch_level<2, 0>(tokens, Ebf, Winbf, W1bf, W2bf, b_in, b1, b2,
                               cin, cout, nullptr, L, first, stream);
        else if (!last)
            launch_level<1, 0>(tokens, Ebf, Winbf, W1bf, W2bf, b_in, b1, b2,
                               cin, cout, nullptr, L, first, stream);
        else
            launch_level<1, 1>(tokens, Ebf, Winbf, W1bf, W2bf, b_in, b1, b2,
                               cin, cout, out, L, first, stream);
        cin = cout;
        cout = (cout == curA) ? curB : curA;
        first = 0;
    }
}